// Round 1
// baseline (3262.758 us; speedup 1.0000x reference)
//
#include <hip/hip_runtime.h>

#define NUSERS  200000
#define NMOVIES 200000

// ---------------------------------------------------------------------------
// Phase 1: um edges. One wave per edge, lane = channel.
//   movie side (src=um0=a, dst=um1=b, x=movie_x):
//     S2m[b] += movie_x[a]*movie_x[b]   -> out_movie[b][0..63]
//     S1m[b] += movie_x[a]              -> out_movie[b][64..127]
//     cntm[b] += 1
//   user side (reversed: src=b, dst=a, x=user_x):
//     S2u[a] += user_x[a]*user_x[b]     -> out_user[a][0..63]
//     S1u[a] += user_x[b]               -> out_user[a][64..127]
//     cntu[a] += 1
// ---------------------------------------------------------------------------
__global__ __launch_bounds__(256) void edge_um_kernel(
    const int* __restrict__ um,
    const float* __restrict__ movie_x,
    const float* __restrict__ user_x,
    float* __restrict__ out_user,
    float* __restrict__ out_movie,
    float* __restrict__ cntm,
    float* __restrict__ cntu,
    int E)
{
    const int lane = threadIdx.x & 63;
    int w = (blockIdx.x * blockDim.x + threadIdx.x) >> 6;
    const int nw = (gridDim.x * blockDim.x) >> 6;
    const int* __restrict__ esrc = um;
    const int* __restrict__ edst = um + E;
    for (int e = w; e < E; e += nw) {
        const int a = esrc[e];
        const int b = edst[e];
        const float xma = movie_x[a * 64 + lane];
        const float xmb = movie_x[b * 64 + lane];
        const float xua = user_x[a * 64 + lane];
        const float xub = user_x[b * 64 + lane];
        atomicAdd(&out_movie[b * 128 + lane],      xma * xmb);  // S2m
        atomicAdd(&out_movie[b * 128 + 64 + lane], xma);        // S1m
        atomicAdd(&out_user[a * 128 + lane],       xua * xub);  // S2u
        atomicAdd(&out_user[a * 128 + 64 + lane],  xub);        // S1u
        if (lane == 0) {
            atomicAdd(&cntm[b], 1.0f);
            atomicAdd(&cntu[a], 1.0f);
        }
    }
}

// ---------------------------------------------------------------------------
// Phase 2: me edges (RGCN aggregation). S_e[d] += entity_x[s]; cnt_e[d] += 1.
// Only dst < NMOVIES matters for the output slice entity_msg[:NMOVIES].
// ---------------------------------------------------------------------------
__global__ __launch_bounds__(256) void edge_me_kernel(
    const int* __restrict__ me,
    const float* __restrict__ entity_x,
    float* __restrict__ S_e,
    float* __restrict__ cnt_e,
    int E)
{
    const int lane = threadIdx.x & 63;
    int w = (blockIdx.x * blockDim.x + threadIdx.x) >> 6;
    const int nw = (gridDim.x * blockDim.x) >> 6;
    const int* __restrict__ esrc = me;
    const int* __restrict__ edst = me + E;
    for (int e = w; e < E; e += nw) {
        const int s = esrc[e];
        const int d = edst[e];
        if (d < NMOVIES) {
            atomicAdd(&S_e[d * 64 + lane], entity_x[s * 64 + lane]);
            if (lane == 0) atomicAdd(&cnt_e[d], 1.0f);
        }
    }
}

// ---------------------------------------------------------------------------
// Phase 3: finalize movies. One wave per row.
// out_movie[m][0..63]  = movie_x[m]
// out_movie[m][64..127] = S1m@W1 + S2m@W2 + cntm*(b1+b2)
//                       + (S_e@Wrel)/max(cnt_e,1) + entity_x[m]@Wroot + brgcn
// ---------------------------------------------------------------------------
__global__ __launch_bounds__(256) void finalize_movie_kernel(
    const float* __restrict__ movie_x,
    const float* __restrict__ entity_x,
    const float* __restrict__ S_e,
    const float* __restrict__ cntm,
    const float* __restrict__ cnt_e,
    const float* __restrict__ W1, const float* __restrict__ b1,
    const float* __restrict__ W2, const float* __restrict__ b2,
    const float* __restrict__ Wrel, const float* __restrict__ Wroot,
    const float* __restrict__ brgcn,
    float* __restrict__ out_movie)
{
    __shared__ float W1s[4096], W2s[4096], Wrels[4096], Wroots[4096];
    __shared__ float bias[64], br[64];
    for (int i = threadIdx.x; i < 4096; i += blockDim.x) {
        W1s[i] = W1[i];
        W2s[i] = W2[i];
        Wrels[i] = Wrel[i];
        Wroots[i] = Wroot[i];
    }
    if (threadIdx.x < 64) {
        bias[threadIdx.x] = b1[threadIdx.x] + b2[threadIdx.x];
        br[threadIdx.x] = brgcn[threadIdx.x];
    }
    __syncthreads();

    const int lane = threadIdx.x & 63;
    int w = (blockIdx.x * blockDim.x + threadIdx.x) >> 6;
    const int nw = (gridDim.x * blockDim.x) >> 6;
    for (int m = w; m < NMOVIES; m += nw) {
        const float s2 = out_movie[m * 128 + lane];        // S2m
        const float s1 = out_movie[m * 128 + 64 + lane];   // S1m
        const float se = S_e[m * 64 + lane];
        const float ex = entity_x[m * 64 + lane];
        const float mx = movie_x[m * 64 + lane];
        const float cm = cntm[m];
        const float inv_ce = 1.0f / fmaxf(cnt_e[m], 1.0f);
        float a1 = 0.f, a2 = 0.f, a3 = 0.f, a4 = 0.f;
#pragma unroll
        for (int k = 0; k < 64; ++k) {
            a1 += __shfl(s1, k) * W1s[k * 64 + lane];
            a2 += __shfl(s2, k) * W2s[k * 64 + lane];
            a3 += __shfl(se, k) * Wrels[k * 64 + lane];
            a4 += __shfl(ex, k) * Wroots[k * 64 + lane];
        }
        const float val = a1 + a2 + cm * bias[lane] + a3 * inv_ce + a4 + br[lane];
        out_movie[m * 128 + lane] = mx;
        out_movie[m * 128 + 64 + lane] = val;
    }
}

// ---------------------------------------------------------------------------
// Phase 4: finalize users. One wave per row.
// out_user[u][0..63]   = user_x[u]
// out_user[u][64..127] = S1u@W1 + S2u@W2 + cntu*(b1+b2)
// ---------------------------------------------------------------------------
__global__ __launch_bounds__(256) void finalize_user_kernel(
    const float* __restrict__ user_x,
    const float* __restrict__ cntu,
    const float* __restrict__ W1, const float* __restrict__ b1,
    const float* __restrict__ W2, const float* __restrict__ b2,
    float* __restrict__ out_user)
{
    __shared__ float W1s[4096], W2s[4096];
    __shared__ float bias[64];
    for (int i = threadIdx.x; i < 4096; i += blockDim.x) {
        W1s[i] = W1[i];
        W2s[i] = W2[i];
    }
    if (threadIdx.x < 64) {
        bias[threadIdx.x] = b1[threadIdx.x] + b2[threadIdx.x];
    }
    __syncthreads();

    const int lane = threadIdx.x & 63;
    int w = (blockIdx.x * blockDim.x + threadIdx.x) >> 6;
    const int nw = (gridDim.x * blockDim.x) >> 6;
    for (int u = w; u < NUSERS; u += nw) {
        const float s2 = out_user[u * 128 + lane];        // S2u
        const float s1 = out_user[u * 128 + 64 + lane];   // S1u
        const float ux = user_x[u * 64 + lane];
        const float cu = cntu[u];
        float a1 = 0.f, a2 = 0.f;
#pragma unroll
        for (int k = 0; k < 64; ++k) {
            a1 += __shfl(s1, k) * W1s[k * 64 + lane];
            a2 += __shfl(s2, k) * W2s[k * 64 + lane];
        }
        const float val = a1 + a2 + cu * bias[lane];
        out_user[u * 128 + lane] = ux;
        out_user[u * 128 + 64 + lane] = val;
    }
}

extern "C" void kernel_launch(void* const* d_in, const int* in_sizes, int n_in,
                              void* d_out, int out_size, void* d_ws, size_t ws_size,
                              hipStream_t stream)
{
    const float* user_x   = (const float*)d_in[0];
    const float* movie_x  = (const float*)d_in[1];
    const float* entity_x = (const float*)d_in[2];
    const int*   um       = (const int*)d_in[3];
    const int*   me       = (const int*)d_in[4];
    const float* W1       = (const float*)d_in[5];
    const float* b1       = (const float*)d_in[6];
    const float* W2       = (const float*)d_in[7];
    const float* b2       = (const float*)d_in[8];
    const float* Wrel     = (const float*)d_in[9];
    const float* Wroot    = (const float*)d_in[10];
    const float* brgcn    = (const float*)d_in[11];

    const int E_um = in_sizes[3] / 2;
    const int E_me = in_sizes[4] / 2;

    float* out_user  = (float*)d_out;                         // [NUSERS, 128]
    float* out_movie = out_user + (size_t)NUSERS * 128;       // [NMOVIES, 128]

    // Workspace layout (floats): S_e[NMOVIES*64], cntm, cntu, cnt_e
    float* S_e   = (float*)d_ws;
    float* cntm  = S_e + (size_t)NMOVIES * 64;
    float* cntu  = cntm + NMOVIES;
    float* cnt_e = cntu + NUSERS;
    const size_t ws_used = ((size_t)NMOVIES * 64 + NMOVIES + NUSERS + NMOVIES) * sizeof(float);

    // Zero accumulators (d_out doubles as the S1/S2 accumulator space).
    hipMemsetAsync(d_out, 0, (size_t)out_size * sizeof(float), stream);
    hipMemsetAsync(d_ws, 0, ws_used, stream);

    edge_um_kernel<<<2048, 256, 0, stream>>>(um, movie_x, user_x, out_user,
                                             out_movie, cntm, cntu, E_um);
    edge_me_kernel<<<2048, 256, 0, stream>>>(me, entity_x, S_e, cnt_e, E_me);
    finalize_movie_kernel<<<4096, 256, 0, stream>>>(movie_x, entity_x, S_e, cntm,
                                                    cnt_e, W1, b1, W2, b2, Wrel,
                                                    Wroot, brgcn, out_movie);
    finalize_user_kernel<<<4096, 256, 0, stream>>>(user_x, cntu, W1, b1, W2, b2,
                                                   out_user);
}

// Round 2
// 1527.017 us; speedup vs baseline: 2.1367x; 2.1367x over previous
//
#include <hip/hip_runtime.h>

#define NUSERS  200000
#define NMOVIES 200000
#define NROWSF1 (NUSERS + NMOVIES)

// ---------------------------------------------------------------------------
// Phase 1: um edges. One wave per edge, lane = channel.
//   movie side: S2m[b]+=xm[a]*xm[b] -> out_movie[b][0..63]
//               S1m[b]+=xm[a]       -> out_movie[b][64..127], cntm[b]+=1
//   user side (reversed): S2u[a]+=xu[a]*xu[b] -> out_user[a][0..63]
//               S1u[a]+=xu[b]       -> out_user[a][64..127], cntu[a]+=1
// ---------------------------------------------------------------------------
__global__ __launch_bounds__(256) void edge_um_kernel(
    const int* __restrict__ um,
    const float* __restrict__ movie_x,
    const float* __restrict__ user_x,
    float* __restrict__ out_user,
    float* __restrict__ out_movie,
    float* __restrict__ cntm,
    float* __restrict__ cntu,
    int E)
{
    const int lane = threadIdx.x & 63;
    int w = (blockIdx.x * blockDim.x + threadIdx.x) >> 6;
    const int nw = (gridDim.x * blockDim.x) >> 6;
    const int* __restrict__ esrc = um;
    const int* __restrict__ edst = um + E;
    for (int e = w; e < E; e += nw) {
        const int a = esrc[e];
        const int b = edst[e];
        const float xma = movie_x[a * 64 + lane];
        const float xmb = movie_x[b * 64 + lane];
        const float xua = user_x[a * 64 + lane];
        const float xub = user_x[b * 64 + lane];
        atomicAdd(&out_movie[b * 128 + lane],      xma * xmb);  // S2m
        atomicAdd(&out_movie[b * 128 + 64 + lane], xma);        // S1m
        atomicAdd(&out_user[a * 128 + lane],       xua * xub);  // S2u
        atomicAdd(&out_user[a * 128 + 64 + lane],  xub);        // S1u
        if (lane == 0) {
            atomicAdd(&cntm[b], 1.0f);
            atomicAdd(&cntu[a], 1.0f);
        }
    }
}

// ---------------------------------------------------------------------------
// Phase 2: me edges (RGCN agg). S_e[d] += entity_x[s]; cnt_e[d] += 1 (d<NMOVIES)
// ---------------------------------------------------------------------------
__global__ __launch_bounds__(256) void edge_me_kernel(
    const int* __restrict__ me,
    const float* __restrict__ entity_x,
    float* __restrict__ S_e,
    float* __restrict__ cnt_e,
    int E)
{
    const int lane = threadIdx.x & 63;
    int w = (blockIdx.x * blockDim.x + threadIdx.x) >> 6;
    const int nw = (gridDim.x * blockDim.x) >> 6;
    const int* __restrict__ esrc = me;
    const int* __restrict__ edst = me + E;
    for (int e = w; e < E; e += nw) {
        const int s = esrc[e];
        const int d = edst[e];
        if (d < NMOVIES) {
            atomicAdd(&S_e[d * 64 + lane], entity_x[s * 64 + lane]);
            if (lane == 0) atomicAdd(&cnt_e[d], 1.0f);
        }
    }
}

// ---------------------------------------------------------------------------
// Phase 3 (F1): NGCF transform for ALL 400k rows (users then movies).
// Thread owns output column c=lane; W1/W2 columns live in registers.
// out[r][0..63]   = x[r]
// out[r][64..127] = S1@W1 + S2@W2 + cnt*(b1+b2)     (movies: partial, F2 adds)
// ---------------------------------------------------------------------------
__global__ __launch_bounds__(256, 2) void finalize_ngcf_kernel(
    const float* __restrict__ user_x,
    const float* __restrict__ movie_x,
    const float* __restrict__ cntu,
    const float* __restrict__ cntm,
    const float* __restrict__ W1, const float* __restrict__ b1,
    const float* __restrict__ W2, const float* __restrict__ b2,
    float* __restrict__ out_user, float* __restrict__ out_movie)
{
    __shared__ float srow[4][128];
    __shared__ float biass[64];
    const int lane = threadIdx.x & 63;
    const int wslot = threadIdx.x >> 6;
    if (threadIdx.x < 64) biass[threadIdx.x] = b1[threadIdx.x] + b2[threadIdx.x];
    __syncthreads();

    // W columns in registers (static indexing only -> stays in VGPRs)
    float Wc1[64], Wc2[64];
#pragma unroll
    for (int k = 0; k < 64; ++k) {
        Wc1[k] = W1[k * 64 + lane];
        Wc2[k] = W2[k * 64 + lane];
    }
    const float bv = biass[lane];

    const int gw = (blockIdx.x * blockDim.x + threadIdx.x) >> 6;
    const int nw = (gridDim.x * blockDim.x) >> 6;

    int r = gw;
    if (r >= NROWSF1) return;

    // prologue: load row r
    float2 v; float xv, cnt;
    {
        const bool isU = r < NUSERS;
        const int row = isU ? r : r - NUSERS;
        const float* outp = (isU ? out_user : out_movie) + (size_t)row * 128;
        v = ((const float2*)outp)[lane];
        xv = ((isU ? user_x : movie_x) + (size_t)row * 64)[lane];
        cnt = (isU ? cntu : cntm)[row];
    }

    while (r < NROWSF1) {
        // stage current row into this wave's LDS slot
        ((float2*)&srow[wslot][0])[lane] = v;

        // prefetch next row's globals (hidden under the FMA phase)
        const int rn = r + nw;
        float2 vn; float xvn = 0.f, cntn = 0.f;
        vn.x = 0.f; vn.y = 0.f;
        if (rn < NROWSF1) {
            const bool isU = rn < NUSERS;
            const int row = isU ? rn : rn - NUSERS;
            const float* outp = (isU ? out_user : out_movie) + (size_t)row * 128;
            vn = ((const float2*)outp)[lane];
            xvn = ((isU ? user_x : movie_x) + (size_t)row * 64)[lane];
            cntn = (isU ? cntu : cntm)[row];
        }

        // broadcast-read s vectors, 4 independent FMA chains
        const float* s2p = &srow[wslot][0];    // cols 0..63  = S2
        const float* s1p = &srow[wslot][64];   // cols 64..127 = S1
        float a1a = 0.f, a1b = 0.f, a2a = 0.f, a2b = 0.f;
#pragma unroll
        for (int k = 0; k < 64; k += 4) {
            const float4 s2v = *(const float4*)&s2p[k];
            const float4 s1v = *(const float4*)&s1p[k];
            a2a = fmaf(s2v.x, Wc2[k],     a2a);
            a2b = fmaf(s2v.y, Wc2[k + 1], a2b);
            a2a = fmaf(s2v.z, Wc2[k + 2], a2a);
            a2b = fmaf(s2v.w, Wc2[k + 3], a2b);
            a1a = fmaf(s1v.x, Wc1[k],     a1a);
            a1b = fmaf(s1v.y, Wc1[k + 1], a1b);
            a1a = fmaf(s1v.z, Wc1[k + 2], a1a);
            a1b = fmaf(s1v.w, Wc1[k + 3], a1b);
        }

        {
            const bool isU = r < NUSERS;
            const int row = isU ? r : r - NUSERS;
            float* outp = (isU ? out_user : out_movie) + (size_t)row * 128;
            outp[lane] = xv;
            outp[64 + lane] = a1a + a1b + a2a + a2b + cnt * bv;
        }
        r = rn;
        v = vn; xv = xvn; cnt = cntn;
    }
}

// ---------------------------------------------------------------------------
// Phase 4 (F2): RGCN transform added into movie rows.
// out_movie[m][64..127] += (Se@Wrel)/max(ce,1) + Ex@Wroot + brgcn
// ---------------------------------------------------------------------------
__global__ __launch_bounds__(256, 2) void finalize_rgcn_kernel(
    const float* __restrict__ entity_x,
    const float* __restrict__ S_e,
    const float* __restrict__ cnt_e,
    const float* __restrict__ Wrel, const float* __restrict__ Wroot,
    const float* __restrict__ brgcn,
    float* __restrict__ out_movie)
{
    __shared__ float srow[4][128];
    __shared__ float brs[64];
    const int lane = threadIdx.x & 63;
    const int wslot = threadIdx.x >> 6;
    if (threadIdx.x < 64) brs[threadIdx.x] = brgcn[threadIdx.x];
    __syncthreads();

    float Wcr[64], Wco[64];
#pragma unroll
    for (int k = 0; k < 64; ++k) {
        Wcr[k] = Wrel[k * 64 + lane];
        Wco[k] = Wroot[k * 64 + lane];
    }
    const float bv = brs[lane];

    const int gw = (blockIdx.x * blockDim.x + threadIdx.x) >> 6;
    const int nw = (gridDim.x * blockDim.x) >> 6;

    int m = gw;
    if (m >= NMOVIES) return;

    float sev, exv, ce;
    sev = S_e[(size_t)m * 64 + lane];
    exv = entity_x[(size_t)m * 64 + lane];
    ce  = cnt_e[m];

    while (m < NMOVIES) {
        srow[wslot][lane]      = sev;
        srow[wslot][64 + lane] = exv;

        const int mn = m + nw;
        float sevn = 0.f, exvn = 0.f, cen = 0.f;
        if (mn < NMOVIES) {
            sevn = S_e[(size_t)mn * 64 + lane];
            exvn = entity_x[(size_t)mn * 64 + lane];
            cen  = cnt_e[mn];
        }

        const float* sep = &srow[wslot][0];
        const float* exp_ = &srow[wslot][64];
        float a3a = 0.f, a3b = 0.f, a4a = 0.f, a4b = 0.f;
#pragma unroll
        for (int k = 0; k < 64; k += 4) {
            const float4 sv = *(const float4*)&sep[k];
            const float4 ev = *(const float4*)&exp_[k];
            a3a = fmaf(sv.x, Wcr[k],     a3a);
            a3b = fmaf(sv.y, Wcr[k + 1], a3b);
            a3a = fmaf(sv.z, Wcr[k + 2], a3a);
            a3b = fmaf(sv.w, Wcr[k + 3], a3b);
            a4a = fmaf(ev.x, Wco[k],     a4a);
            a4b = fmaf(ev.y, Wco[k + 1], a4b);
            a4a = fmaf(ev.z, Wco[k + 2], a4a);
            a4b = fmaf(ev.w, Wco[k + 3], a4b);
        }

        const float inv_ce = 1.0f / fmaxf(ce, 1.0f);
        float* outp = out_movie + (size_t)m * 128;
        outp[64 + lane] += (a3a + a3b) * inv_ce + a4a + a4b + bv;

        m = mn;
        sev = sevn; exv = exvn; ce = cen;
    }
}

extern "C" void kernel_launch(void* const* d_in, const int* in_sizes, int n_in,
                              void* d_out, int out_size, void* d_ws, size_t ws_size,
                              hipStream_t stream)
{
    const float* user_x   = (const float*)d_in[0];
    const float* movie_x  = (const float*)d_in[1];
    const float* entity_x = (const float*)d_in[2];
    const int*   um       = (const int*)d_in[3];
    const int*   me       = (const int*)d_in[4];
    const float* W1       = (const float*)d_in[5];
    const float* b1       = (const float*)d_in[6];
    const float* W2       = (const float*)d_in[7];
    const float* b2       = (const float*)d_in[8];
    const float* Wrel     = (const float*)d_in[9];
    const float* Wroot    = (const float*)d_in[10];
    const float* brgcn    = (const float*)d_in[11];

    const int E_um = in_sizes[3] / 2;
    const int E_me = in_sizes[4] / 2;

    float* out_user  = (float*)d_out;                         // [NUSERS, 128]
    float* out_movie = out_user + (size_t)NUSERS * 128;       // [NMOVIES, 128]

    // Workspace layout (floats): S_e[NMOVIES*64], cntm, cntu, cnt_e
    float* S_e   = (float*)d_ws;
    float* cntm  = S_e + (size_t)NMOVIES * 64;
    float* cntu  = cntm + NMOVIES;
    float* cnt_e = cntu + NUSERS;
    const size_t ws_used = ((size_t)NMOVIES * 64 + NMOVIES + NUSERS + NMOVIES) * sizeof(float);

    // Zero accumulators (d_out doubles as the S1/S2 accumulator space).
    hipMemsetAsync(d_out, 0, (size_t)out_size * sizeof(float), stream);
    hipMemsetAsync(d_ws, 0, ws_used, stream);

    edge_um_kernel<<<2048, 256, 0, stream>>>(um, movie_x, user_x, out_user,
                                             out_movie, cntm, cntu, E_um);
    edge_me_kernel<<<2048, 256, 0, stream>>>(me, entity_x, S_e, cnt_e, E_me);
    finalize_ngcf_kernel<<<2048, 256, 0, stream>>>(user_x, movie_x, cntu, cntm,
                                                   W1, b1, W2, b2,
                                                   out_user, out_movie);
    finalize_rgcn_kernel<<<2048, 256, 0, stream>>>(entity_x, S_e, cnt_e,
                                                   Wrel, Wroot, brgcn, out_movie);
}

// Round 3
// 1083.846 us; speedup vs baseline: 3.0104x; 1.4089x over previous
//
#include <hip/hip_runtime.h>

#define NUSERS  200000
#define NMOVIES 200000
#define NROWSF1 (NUSERS + NMOVIES)

// ---------------------------------------------------------------------------
// Edge phase (merged um + me). One wave per edge, lane = channel.
//  um edge (a,b):
//    S1m[b] += movie_x[a]  -> out_movie[b][64..127], cntm[b]+=1
//    S1u[a] += user_x[b]   -> out_user[a][64..127],  cntu[a]+=1
//  (S2 is NOT accumulated: S2[i] = x[i] ⊙ S1[i], computed in finalize.)
//  me edge (s,d):  S_e[d] += entity_x[s] -> out_movie[d][0..63], cnt_e[d]+=1
// ---------------------------------------------------------------------------
__global__ __launch_bounds__(256) void edge_kernel(
    const int* __restrict__ um,
    const int* __restrict__ me,
    const float* __restrict__ movie_x,
    const float* __restrict__ user_x,
    const float* __restrict__ entity_x,
    float* __restrict__ out_user,
    float* __restrict__ out_movie,
    float* __restrict__ cntm,
    float* __restrict__ cntu,
    float* __restrict__ cnt_e,
    int E_um, int E_me)
{
    const int lane = threadIdx.x & 63;
    int w = (blockIdx.x * blockDim.x + threadIdx.x) >> 6;
    const int nw = (gridDim.x * blockDim.x) >> 6;
    const int total = E_um + E_me;
    for (int t = w; t < total; t += nw) {
        if (t < E_um) {
            const int a = um[t];
            const int b = um[E_um + t];
            atomicAdd(&out_movie[(size_t)b * 128 + 64 + lane],
                      movie_x[(size_t)a * 64 + lane]);           // S1m
            atomicAdd(&out_user[(size_t)a * 128 + 64 + lane],
                      user_x[(size_t)b * 64 + lane]);            // S1u
            if (lane == 0) {
                atomicAdd(&cntm[b], 1.0f);
                atomicAdd(&cntu[a], 1.0f);
            }
        } else {
            const int e = t - E_um;
            const int s = me[e];
            const int d = me[E_me + e];
            if (d < NMOVIES) {
                atomicAdd(&out_movie[(size_t)d * 128 + lane],
                          entity_x[(size_t)s * 64 + lane]);      // S_e
                if (lane == 0) atomicAdd(&cnt_e[d], 1.0f);
            }
        }
    }
}

// ---------------------------------------------------------------------------
// Finalize A (movies only): RGCN part.
// Reads S_e from out_movie[m][0..63], overwrites it with
//   r = (S_e@Wrel)/max(ce,1) + Ex@Wroot + brgcn
// (added into the final value by finalize B below).
// ---------------------------------------------------------------------------
__global__ __launch_bounds__(256, 2) void finalize_rgcn_kernel(
    const float* __restrict__ entity_x,
    const float* __restrict__ cnt_e,
    const float* __restrict__ Wrel, const float* __restrict__ Wroot,
    const float* __restrict__ brgcn,
    float* __restrict__ out_movie)
{
    __shared__ float srow[4][128];
    __shared__ float brs[64];
    const int lane = threadIdx.x & 63;
    const int wslot = threadIdx.x >> 6;
    if (threadIdx.x < 64) brs[threadIdx.x] = brgcn[threadIdx.x];
    __syncthreads();

    float Wcr[64], Wco[64];
#pragma unroll
    for (int k = 0; k < 64; ++k) {
        Wcr[k] = Wrel[k * 64 + lane];
        Wco[k] = Wroot[k * 64 + lane];
    }
    const float bv = brs[lane];

    const int gw = (blockIdx.x * blockDim.x + threadIdx.x) >> 6;
    const int nw = (gridDim.x * blockDim.x) >> 6;

    int m = gw;
    if (m >= NMOVIES) return;

    float sev = out_movie[(size_t)m * 128 + lane];
    float exv = entity_x[(size_t)m * 64 + lane];
    float ce  = cnt_e[m];

    while (m < NMOVIES) {
        srow[wslot][lane]      = sev;
        srow[wslot][64 + lane] = exv;

        const int mn = m + nw;
        float sevn = 0.f, exvn = 0.f, cen = 0.f;
        if (mn < NMOVIES) {
            sevn = out_movie[(size_t)mn * 128 + lane];
            exvn = entity_x[(size_t)mn * 64 + lane];
            cen  = cnt_e[mn];
        }

        const float* sep = &srow[wslot][0];
        const float* exp_ = &srow[wslot][64];
        float a3a = 0.f, a3b = 0.f, a4a = 0.f, a4b = 0.f;
#pragma unroll
        for (int k = 0; k < 64; k += 4) {
            const float4 sv = *(const float4*)&sep[k];
            const float4 ev = *(const float4*)&exp_[k];
            a3a = fmaf(sv.x, Wcr[k],     a3a);
            a3b = fmaf(sv.y, Wcr[k + 1], a3b);
            a3a = fmaf(sv.z, Wcr[k + 2], a3a);
            a3b = fmaf(sv.w, Wcr[k + 3], a3b);
            a4a = fmaf(ev.x, Wco[k],     a4a);
            a4b = fmaf(ev.y, Wco[k + 1], a4b);
            a4a = fmaf(ev.z, Wco[k + 2], a4a);
            a4b = fmaf(ev.w, Wco[k + 3], a4b);
        }

        const float inv_ce = 1.0f / fmaxf(ce, 1.0f);
        out_movie[(size_t)m * 128 + lane] =
            (a3a + a3b) * inv_ce + a4a + a4b + bv;

        m = mn;
        sev = sevn; exv = exvn; ce = cen;
    }
}

// ---------------------------------------------------------------------------
// Finalize B (all 400k rows): NGCF transform + x-copy + rgcn add.
// out[r][64..127] = S1@W1 + (x ⊙ S1)@W2 + cnt*(b1+b2) + out[r][lane-part]
// out[r][0..63]   = x[r]
// (out[r][0..63] holds rgcn result for movies, zeros for users.)
// ---------------------------------------------------------------------------
__global__ __launch_bounds__(256, 2) void finalize_ngcf_kernel(
    const float* __restrict__ user_x,
    const float* __restrict__ movie_x,
    const float* __restrict__ cntu,
    const float* __restrict__ cntm,
    const float* __restrict__ W1, const float* __restrict__ b1,
    const float* __restrict__ W2, const float* __restrict__ b2,
    float* __restrict__ out_user, float* __restrict__ out_movie)
{
    __shared__ float srow[4][128];
    __shared__ float biass[64];
    const int lane = threadIdx.x & 63;
    const int wslot = threadIdx.x >> 6;
    if (threadIdx.x < 64) biass[threadIdx.x] = b1[threadIdx.x] + b2[threadIdx.x];
    __syncthreads();

    float Wc1[64], Wc2[64];
#pragma unroll
    for (int k = 0; k < 64; ++k) {
        Wc1[k] = W1[k * 64 + lane];
        Wc2[k] = W2[k * 64 + lane];
    }
    const float bv = biass[lane];

    const int gw = (blockIdx.x * blockDim.x + threadIdx.x) >> 6;
    const int nw = (gridDim.x * blockDim.x) >> 6;

    int r = gw;
    if (r >= NROWSF1) return;

    float s1v, xv, cnt, rp;
    {
        const bool isU = r < NUSERS;
        const int row = isU ? r : r - NUSERS;
        float* outp = (isU ? out_user : out_movie) + (size_t)row * 128;
        s1v = outp[64 + lane];
        rp  = outp[lane];
        xv  = ((isU ? user_x : movie_x) + (size_t)row * 64)[lane];
        cnt = (isU ? cntu : cntm)[row];
    }

    while (r < NROWSF1) {
        srow[wslot][lane]      = s1v;
        srow[wslot][64 + lane] = xv;

        const int rn = r + nw;
        float s1n = 0.f, xvn = 0.f, cntn = 0.f, rpn = 0.f;
        if (rn < NROWSF1) {
            const bool isU = rn < NUSERS;
            const int row = isU ? rn : rn - NUSERS;
            float* outp = (isU ? out_user : out_movie) + (size_t)row * 128;
            s1n = outp[64 + lane];
            rpn = outp[lane];
            xvn = ((isU ? user_x : movie_x) + (size_t)row * 64)[lane];
            cntn = (isU ? cntu : cntm)[row];
        }

        const float* s1p = &srow[wslot][0];
        const float* xp  = &srow[wslot][64];
        float a1a = 0.f, a1b = 0.f, a2a = 0.f, a2b = 0.f;
#pragma unroll
        for (int k = 0; k < 64; k += 4) {
            const float4 s1q = *(const float4*)&s1p[k];
            const float4 xq  = *(const float4*)&xp[k];
            a1a = fmaf(s1q.x, Wc1[k],     a1a);
            a1b = fmaf(s1q.y, Wc1[k + 1], a1b);
            a1a = fmaf(s1q.z, Wc1[k + 2], a1a);
            a1b = fmaf(s1q.w, Wc1[k + 3], a1b);
            a2a = fmaf(xq.x * s1q.x, Wc2[k],     a2a);
            a2b = fmaf(xq.y * s1q.y, Wc2[k + 1], a2b);
            a2a = fmaf(xq.z * s1q.z, Wc2[k + 2], a2a);
            a2b = fmaf(xq.w * s1q.w, Wc2[k + 3], a2b);
        }

        {
            const bool isU = r < NUSERS;
            const int row = isU ? r : r - NUSERS;
            float* outp = (isU ? out_user : out_movie) + (size_t)row * 128;
            outp[lane] = xv;
            outp[64 + lane] = a1a + a1b + a2a + a2b + cnt * bv + rp;
        }
        r = rn;
        s1v = s1n; xv = xvn; cnt = cntn; rp = rpn;
    }
}

extern "C" void kernel_launch(void* const* d_in, const int* in_sizes, int n_in,
                              void* d_out, int out_size, void* d_ws, size_t ws_size,
                              hipStream_t stream)
{
    const float* user_x   = (const float*)d_in[0];
    const float* movie_x  = (const float*)d_in[1];
    const float* entity_x = (const float*)d_in[2];
    const int*   um       = (const int*)d_in[3];
    const int*   me       = (const int*)d_in[4];
    const float* W1       = (const float*)d_in[5];
    const float* b1       = (const float*)d_in[6];
    const float* W2       = (const float*)d_in[7];
    const float* b2       = (const float*)d_in[8];
    const float* Wrel     = (const float*)d_in[9];
    const float* Wroot    = (const float*)d_in[10];
    const float* brgcn    = (const float*)d_in[11];

    const int E_um = in_sizes[3] / 2;
    const int E_me = in_sizes[4] / 2;

    float* out_user  = (float*)d_out;                         // [NUSERS, 128]
    float* out_movie = out_user + (size_t)NUSERS * 128;       // [NMOVIES, 128]

    // Workspace (floats): cntm, cntu, cnt_e only.
    float* cntm  = (float*)d_ws;
    float* cntu  = cntm + NMOVIES;
    float* cnt_e = cntu + NUSERS;
    const size_t ws_used = ((size_t)NMOVIES + NUSERS + NMOVIES) * sizeof(float);

    // Zero accumulators (d_out doubles as S1 / S_e accumulator space).
    hipMemsetAsync(d_out, 0, (size_t)out_size * sizeof(float), stream);
    hipMemsetAsync(d_ws, 0, ws_used, stream);

    edge_kernel<<<2048, 256, 0, stream>>>(um, me, movie_x, user_x, entity_x,
                                          out_user, out_movie,
                                          cntm, cntu, cnt_e, E_um, E_me);
    finalize_rgcn_kernel<<<2048, 256, 0, stream>>>(entity_x, cnt_e,
                                                   Wrel, Wroot, brgcn, out_movie);
    finalize_ngcf_kernel<<<4096, 256, 0, stream>>>(user_x, movie_x, cntu, cntm,
                                                   W1, b1, W2, b2,
                                                   out_user, out_movie);
}